// Round 1
// baseline (261.182 us; speedup 1.0000x reference)
//
#include <hip/hip_runtime.h>
#include <hip/hip_bf16.h>

#define BB 128
#define NN 512
#define IND 128
#define LD 64
#define NC 10
#define FL 4
#define ROWS (BB*NN)          // 65536

// workspace layout (floats)
#define OFF_RDEG 0
#define OFF_HW   (OFF_RDEG + ROWS)            // hw_s: [B,N,64] pre-scaled hs@W_s
#define OFF_H    (OFF_HW + ROWS*LD)           // h:    [B,N,64]
#define OFF_HM   (OFF_H + ROWS*LD)            // hm_s: [B,N]
#define OFF_HV   (OFF_HM + ROWS)              // hv_s: [B,N]
#define OFF_ZS   (OFF_HV + ROWS)              // zs:   [B,N]
#define OFF_ZSS  (OFF_ZS + ROWS)              // zs_s: [B,N]
#define OFF_KLP  (OFF_ZSS + ROWS)             // kl partials [16384]
#define OFF_MSEP (OFF_KLP + 16384)            // mse partials [16384]
#define OFF_HG   (OFF_MSEP + 16384)           // hg: [B,64]

__device__ inline float wave_reduce(float v) {
    #pragma unroll
    for (int m = 32; m; m >>= 1) v += __shfl_xor(v, m, 64);
    return v;
}

// K1: deg[b,i] = sum_j gs[b,i,j]; store reciprocal
__global__ void k_deg(const float* __restrict__ gs, float* __restrict__ rdeg) {
    int gid = blockIdx.x * blockDim.x + threadIdx.x;
    int row = gid >> 6, lane = gid & 63;
    const float4* r4 = (const float4*)(gs + (size_t)row * NN);
    float4 a = r4[lane], b = r4[lane + 64];
    float s = a.x + a.y + a.z + a.w + b.x + b.y + b.z + b.w;
    s = wave_reduce(s);
    if (lane == 0) rdeg[row] = 1.0f / s;
}

// K2: hw_s[b,j,l] = rdeg[b,j] * sum_f hs[b,j,f] * W_s[f,l]
__global__ __launch_bounds__(256) void k_hw(const float* __restrict__ hs,
                                            const float* __restrict__ W_s,
                                            const float* __restrict__ rdeg,
                                            float* __restrict__ hw_s) {
    __shared__ float sW[IND * LD];       // 32 KB
    __shared__ float shs[16 * 132];      // 16 rows padded
    int t = threadIdx.x;
    for (int i = t; i < IND * LD; i += 256) sW[i] = W_s[i];
    int row0 = blockIdx.x * 16;
    for (int i = t; i < 16 * IND; i += 256)
        shs[(i >> 7) * 132 + (i & 127)] = hs[(size_t)row0 * IND + i];
    __syncthreads();
    int l = t & 63, rg = t >> 6;   // rg 0..3 -> rows rg*4..rg*4+3
    float acc[4] = {0.f, 0.f, 0.f, 0.f};
    for (int f = 0; f < IND; ++f) {
        float w = sW[f * LD + l];
        #pragma unroll
        for (int r = 0; r < 4; ++r)
            acc[r] += shs[(rg * 4 + r) * 132 + f] * w;
    }
    #pragma unroll
    for (int r = 0; r < 4; ++r) {
        int row = row0 + rg * 4 + r;
        hw_s[(size_t)row * LD + l] = acc[r] * rdeg[row];
    }
}

// K3: h[b,i,l] = relu(sum_j gs[b,i,j] * hw_s[b,j,l] + b_s[l])
// per-batch GEMM M=512 N=64 K=512; block computes 64x64 tile
#define KT 32
__global__ __launch_bounds__(256) void k_gemm_h(const float* __restrict__ gs,
                                                const float* __restrict__ hw_s,
                                                const float* __restrict__ b_s,
                                                float* __restrict__ h) {
    __shared__ float sAT[KT][68];   // [k][i] transposed A tile
    __shared__ float sB[KT][68];    // [k][l]
    int b = blockIdx.y, m0 = blockIdx.x * 64;
    int t = threadIdx.x;
    int ty = t >> 4, tx = t & 15;   // 16x16 threads, 4x4 micro-tile
    const float* gsb = gs + ((size_t)b * NN + m0) * NN;
    const float* hwb = hw_s + (size_t)b * NN * LD;
    float acc[4][4] = {{0.f}};
    int ai = t >> 2, aq = (t & 3) * 8;       // A: row ai, k-cols aq..aq+7
    int bk = t >> 3, bc = (t & 7) * 8;       // B: row bk, cols bc..bc+7
    for (int k0 = 0; k0 < NN; k0 += KT) {
        float4 a0 = *(const float4*)(gsb + (size_t)ai * NN + k0 + aq);
        float4 a1 = *(const float4*)(gsb + (size_t)ai * NN + k0 + aq + 4);
        float4 b0 = *(const float4*)(hwb + (size_t)k0 * LD + t * 8);
        float4 b1 = *(const float4*)(hwb + (size_t)k0 * LD + t * 8 + 4);
        __syncthreads();
        sAT[aq + 0][ai] = a0.x; sAT[aq + 1][ai] = a0.y;
        sAT[aq + 2][ai] = a0.z; sAT[aq + 3][ai] = a0.w;
        sAT[aq + 4][ai] = a1.x; sAT[aq + 5][ai] = a1.y;
        sAT[aq + 6][ai] = a1.z; sAT[aq + 7][ai] = a1.w;
        *(float4*)&sB[bk][bc] = b0;
        *(float4*)&sB[bk][bc + 4] = b1;
        __syncthreads();
        #pragma unroll
        for (int k = 0; k < KT; ++k) {
            float4 av = *(const float4*)&sAT[k][ty * 4];
            float4 bv = *(const float4*)&sB[k][tx * 4];
            acc[0][0] += av.x * bv.x; acc[0][1] += av.x * bv.y;
            acc[0][2] += av.x * bv.z; acc[0][3] += av.x * bv.w;
            acc[1][0] += av.y * bv.x; acc[1][1] += av.y * bv.y;
            acc[1][2] += av.y * bv.z; acc[1][3] += av.y * bv.w;
            acc[2][0] += av.z * bv.x; acc[2][1] += av.z * bv.y;
            acc[2][2] += av.z * bv.z; acc[2][3] += av.z * bv.w;
            acc[3][0] += av.w * bv.x; acc[3][1] += av.w * bv.y;
            acc[3][2] += av.w * bv.z; acc[3][3] += av.w * bv.w;
        }
    }
    #pragma unroll
    for (int r = 0; r < 4; ++r) {
        int row = m0 + ty * 4 + r;
        float4 o;
        o.x = fmaxf(acc[r][0] + b_s[tx * 4 + 0], 0.f);
        o.y = fmaxf(acc[r][1] + b_s[tx * 4 + 1], 0.f);
        o.z = fmaxf(acc[r][2] + b_s[tx * 4 + 2], 0.f);
        o.w = fmaxf(acc[r][3] + b_s[tx * 4 + 3], 0.f);
        *(float4*)&h[((size_t)b * NN + row) * LD + tx * 4] = o;
    }
}

// K4: hm_s[b,j] = rdeg[b,j]*sum_l h[b,j,l]*W_mu[l];  hv_s likewise
__global__ void k_hmv(const float* __restrict__ h, const float* __restrict__ W_mu,
                      const float* __restrict__ W_lv, const float* __restrict__ rdeg,
                      float* __restrict__ hm_s, float* __restrict__ hv_s) {
    int gid = blockIdx.x * blockDim.x + threadIdx.x;
    int row = gid >> 6, lane = gid & 63;
    float hv = h[(size_t)row * LD + lane];
    float m = wave_reduce(hv * W_mu[lane]);
    float v = wave_reduce(hv * W_lv[lane]);
    if (lane == 0) {
        float rd = rdeg[row];
        hm_s[row] = m * rd;
        hv_s[row] = v * rd;
    }
}

// K5: mu/lv matvec over gs + flow epilogue -> zs, zs_s, kl partials
__global__ void k_muflow(const float* __restrict__ gs, const float* __restrict__ hm_s,
                         const float* __restrict__ hv_s, const float* __restrict__ eps,
                         const float* __restrict__ b_mu, const float* __restrict__ b_lv,
                         const float* __restrict__ beta, const float* __restrict__ fw,
                         const float* __restrict__ fb, const float* __restrict__ fs,
                         const float* __restrict__ rdeg,
                         float* __restrict__ zs, float* __restrict__ zs_s,
                         float* __restrict__ kl_part) {
    __shared__ float skl[4];
    int t = threadIdx.x;
    int gid = blockIdx.x * blockDim.x + t;
    int row = gid >> 6, lane = t & 63, wid = t >> 6;
    int b = row >> 9;
    const float4* g4 = (const float4*)(gs + (size_t)row * NN);
    const float4* m4 = (const float4*)(hm_s + (size_t)b * NN);
    const float4* v4 = (const float4*)(hv_s + (size_t)b * NN);
    float4 ga = g4[lane], gb = g4[lane + 64];
    float4 ma = m4[lane], mb = m4[lane + 64];
    float4 va = v4[lane], vb = v4[lane + 64];
    float sm = ga.x*ma.x + ga.y*ma.y + ga.z*ma.z + ga.w*ma.w
             + gb.x*mb.x + gb.y*mb.y + gb.z*mb.z + gb.w*mb.w;
    float sv = ga.x*va.x + ga.y*va.y + ga.z*va.z + ga.w*va.w
             + gb.x*vb.x + gb.y*vb.y + gb.z*vb.z + gb.w*vb.w;
    sm = wave_reduce(sm);
    sv = wave_reduce(sv);
    if (lane == 0) {
        float mu = fmaxf(sm + b_mu[0], 0.f);
        float lv = fmaxf(sv + b_lv[0], 0.f);
        float sigma = expf(0.5f * lv);
        float z0 = eps[row] * sigma + mu;
        float z = z0, lj = 0.f;
        #pragma unroll
        for (int k = 0; k < FL; ++k) {
            float tt = tanhf(fw[k] * z + fb[k]);
            float det = 1.f + fs[k] * fw[k] * (1.f - tt * tt);
            lj += logf(fabsf(det) + 1e-7f);
            z += fs[k] * tt;
        }
        float e = (z0 - mu) / sigma;
        float logq = -0.5f * e * e - logf(2.5f * sigma);
        float logp = -0.5f * z * z - logf(2.5f);
        float kl = logq - lj - logp;
        float zv = 1.f / (1.f + expf(-beta[0] * z));
        zs[row] = zv;
        zs_s[row] = zv * rdeg[row];
        skl[wid] = kl;
    }
    __syncthreads();
    if (t == 0) kl_part[blockIdx.x] = skl[0] + skl[1] + skl[2] + skl[3];
}

// K6: d_pre matvec over gs + mse epilogue
__global__ void k_dec(const float* __restrict__ gs, const float* __restrict__ zs_s,
                      const float* __restrict__ h, const float* __restrict__ W_dec,
                      const float* __restrict__ b_dec, float* __restrict__ mse_part) {
    __shared__ float sms[4];
    int t = threadIdx.x;
    int gid = blockIdx.x * blockDim.x + t;
    int row = gid >> 6, lane = t & 63, wid = t >> 6;
    int b = row >> 9;
    const float4* g4 = (const float4*)(gs + (size_t)row * NN);
    const float4* z4 = (const float4*)(zs_s + (size_t)b * NN);
    float4 ga = g4[lane], gb = g4[lane + 64];
    float4 za = z4[lane], zb = z4[lane + 64];
    float s = ga.x*za.x + ga.y*za.y + ga.z*za.z + ga.w*za.w
            + gb.x*zb.x + gb.y*zb.y + gb.z*zb.z + gb.w*zb.w;
    s = wave_reduce(s);          // all lanes hold d_pre
    float dval = fmaxf(s * W_dec[lane] + b_dec[lane], 0.f);
    float diff = h[(size_t)row * LD + lane] - dval;
    float ms = wave_reduce(diff * diff);
    if (lane == 0) sms[wid] = ms;
    __syncthreads();
    if (t == 0) mse_part[blockIdx.x] = sms[0] + sms[1] + sms[2] + sms[3];
}

// K7: hg[b,l] = sum_n h[b,n,l] * zs[b,n]
__global__ void k_hg(const float* __restrict__ h, const float* __restrict__ zs,
                     float* __restrict__ hg) {
    __shared__ float red[4][64];
    int b = blockIdx.x;
    int t = threadIdx.x, l = t & 63, c = t >> 6;
    const float* hb = h + (size_t)b * NN * LD;
    const float* zb = zs + (size_t)b * NN;
    float acc = 0.f;
    for (int n = c * 128; n < c * 128 + 128; ++n)
        acc += hb[(size_t)n * LD + l] * zb[n];
    red[c][l] = acc;
    __syncthreads();
    if (c == 0) hg[(size_t)b * LD + l] = red[0][l] + red[1][l] + red[2][l] + red[3][l];
}

// K8: classifier + all final reductions -> out[2]
__global__ __launch_bounds__(256) void k_final(const float* __restrict__ hg,
                                               const float* __restrict__ W1,
                                               const float* __restrict__ b1,
                                               const float* __restrict__ W2,
                                               const float* __restrict__ b2,
                                               const int* __restrict__ labels,
                                               const float* __restrict__ kl_part,
                                               const float* __restrict__ mse_part,
                                               float* __restrict__ out) {
    __shared__ float sx[BB][LD + 1];
    __shared__ float snll[BB];
    __shared__ float scorr[BB];
    __shared__ float sred[256];
    int t = threadIdx.x;
    // x = relu(hg@W1 + b1) for all b: 128*64 tasks
    for (int idx = t; idx < BB * LD; idx += 256) {
        int b = idx >> 6, l2 = idx & 63;
        float acc = b1[l2];
        for (int l = 0; l < LD; ++l) acc += hg[b * LD + l] * W1[l * LD + l2];
        sx[b][l2] = fmaxf(acc, 0.f);
    }
    __syncthreads();
    if (t < BB) {
        int b = t;
        float lg[NC];
        float mx = -1e30f;
        #pragma unroll
        for (int c = 0; c < NC; ++c) {
            float acc = b2[c];
            for (int l = 0; l < LD; ++l) acc += sx[b][l] * W2[l * NC + c];
            lg[c] = acc;
            mx = fmaxf(mx, acc);
        }
        int lab = labels[b];
        float se = 0.f, lab_logit = 0.f;
        #pragma unroll
        for (int c = 0; c < NC; ++c) {
            se += expf(lg[c] - mx);
            if (c == lab) lab_logit = lg[c];
        }
        float lse = mx + logf(se);
        snll[b] = -(lab_logit - lse);
        int pred = 0; float bm = lg[0];
        #pragma unroll
        for (int c = 1; c < NC; ++c) if (lg[c] > bm) { bm = lg[c]; pred = c; }
        scorr[b] = (pred == lab) ? 1.f : 0.f;
    }
    __syncthreads();
    float kacc = 0.f, macc = 0.f;
    for (int i = t; i < 16384; i += 256) { kacc += kl_part[i]; macc += mse_part[i]; }
    sred[t] = kacc; __syncthreads();
    for (int s2 = 128; s2 > 0; s2 >>= 1) { if (t < s2) sred[t] += sred[t + s2]; __syncthreads(); }
    float ksum = sred[0]; __syncthreads();
    sred[t] = macc; __syncthreads();
    for (int s2 = 128; s2 > 0; s2 >>= 1) { if (t < s2) sred[t] += sred[t + s2]; __syncthreads(); }
    float msum = sred[0]; __syncthreads();
    sred[t] = (t < BB) ? snll[t] : 0.f; __syncthreads();
    for (int s2 = 128; s2 > 0; s2 >>= 1) { if (t < s2) sred[t] += sred[t + s2]; __syncthreads(); }
    float nsum = sred[0]; __syncthreads();
    sred[t] = (t < BB) ? scorr[t] : 0.f; __syncthreads();
    for (int s2 = 128; s2 > 0; s2 >>= 1) { if (t < s2) sred[t] += sred[t + s2]; __syncthreads(); }
    if (t == 0) {
        float loss = nsum / (float)BB
                   + msum / ((float)BB * NN * LD)
                   + ksum / ((float)BB * NN);
        out[0] = loss;
        out[1] = sred[0] / (float)BB;
    }
}

extern "C" void kernel_launch(void* const* d_in, const int* in_sizes, int n_in,
                              void* d_out, int out_size, void* d_ws, size_t ws_size,
                              hipStream_t stream) {
    const float* gs    = (const float*)d_in[0];
    const float* hs    = (const float*)d_in[1];
    const int*   labels= (const int*)d_in[2];
    const float* eps   = (const float*)d_in[3];
    const float* W_s   = (const float*)d_in[4];
    const float* b_s   = (const float*)d_in[5];
    const float* W_mu  = (const float*)d_in[6];
    const float* b_mu  = (const float*)d_in[7];
    const float* W_lv  = (const float*)d_in[8];
    const float* b_lv  = (const float*)d_in[9];
    const float* W_dec = (const float*)d_in[10];
    const float* b_dec = (const float*)d_in[11];
    const float* W1    = (const float*)d_in[12];
    const float* b1    = (const float*)d_in[13];
    const float* W2    = (const float*)d_in[14];
    const float* b2    = (const float*)d_in[15];
    const float* beta  = (const float*)d_in[16];
    const float* fw    = (const float*)d_in[17];
    const float* fb    = (const float*)d_in[18];
    const float* fs    = (const float*)d_in[19];

    float* ws     = (float*)d_ws;
    float* rdeg   = ws + OFF_RDEG;
    float* hw_s   = ws + OFF_HW;
    float* h      = ws + OFF_H;
    float* hm_s   = ws + OFF_HM;
    float* hv_s   = ws + OFF_HV;
    float* zs     = ws + OFF_ZS;
    float* zs_s   = ws + OFF_ZSS;
    float* klp    = ws + OFF_KLP;
    float* msep   = ws + OFF_MSEP;
    float* hg     = ws + OFF_HG;

    k_deg<<<ROWS / 4, 256, 0, stream>>>(gs, rdeg);
    k_hw<<<ROWS / 16, 256, 0, stream>>>(hs, W_s, rdeg, hw_s);
    k_gemm_h<<<dim3(8, BB), 256, 0, stream>>>(gs, hw_s, b_s, h);
    k_hmv<<<ROWS / 4, 256, 0, stream>>>(h, W_mu, W_lv, rdeg, hm_s, hv_s);
    k_muflow<<<ROWS / 4, 256, 0, stream>>>(gs, hm_s, hv_s, eps, b_mu, b_lv, beta,
                                           fw, fb, fs, rdeg, zs, zs_s, klp);
    k_dec<<<ROWS / 4, 256, 0, stream>>>(gs, zs_s, h, W_dec, b_dec, msep);
    k_hg<<<BB, 256, 0, stream>>>(h, zs, hg);
    k_final<<<1, 256, 0, stream>>>(hg, W1, b1, W2, b2, labels, klp, msep, (float*)d_out);
}